// Round 3
// baseline (205.812 us; speedup 1.0000x reference)
//
#include <hip/hip_runtime.h>

#define N_PTS 20000
#define NCLS 20
#define KNN 16
#define GRID 12
#define NCELLS (GRID * GRID * GRID)
#define HCELL (1.0f / (float)GRID)
#define CAND_CAP 512       // raw candidates per cell-block (E~313 interior)
#define KEY_CAP 128        // filtered keys per point (E~26)
#define R_TARGET 0.0680f   // radius giving E[cnt]~26 in the interior
#define TAU2MAX ((0.9995f * HCELL) * (0.9995f * HCELL))  // coverage-exact cap

__device__ __forceinline__ int cell1d(float v) {
    int c = (int)(v * (float)GRID);
    return min(max(c, 0), GRID - 1);
}

// ---------------------------------------------------------------------------
// Grid build: histogram -> exclusive scan (1 block) -> scatter (counting sort)
// scatter also gathers logits rows into sorted order (ls) and records orig[].
// ---------------------------------------------------------------------------
__global__ __launch_bounds__(256) void count_kernel(const float* __restrict__ coords,
                                                    int* __restrict__ cellCount) {
    const int p = blockIdx.x * blockDim.x + threadIdx.x;
    if (p >= N_PTS) return;
    const int cx = cell1d(coords[3 * p + 0]);
    const int cy = cell1d(coords[3 * p + 1]);
    const int cz = cell1d(coords[3 * p + 2]);
    atomicAdd(&cellCount[(cz * GRID + cy) * GRID + cx], 1);
}

__global__ __launch_bounds__(256) void scan_kernel(const int* __restrict__ cellCount,
                                                   int* __restrict__ cellStart,
                                                   int* __restrict__ cellCursor) {
    __shared__ int part[256];
    const int t = threadIdx.x;
    const int base = t * 7;                   // 256*7 = 1792 >= 1728
    int local[7];
    int s = 0;
#pragma unroll
    for (int i = 0; i < 7; ++i) {
        const int c = base + i;
        const int v = (c < NCELLS) ? cellCount[c] : 0;
        local[i] = s;
        s += v;
    }
    part[t] = s;
    __syncthreads();
    for (int off = 1; off < 256; off <<= 1) {
        const int v = part[t] + ((t >= off) ? part[t - off] : 0);
        __syncthreads();
        part[t] = v;
        __syncthreads();
    }
    const int excl = (t > 0) ? part[t - 1] : 0;
#pragma unroll
    for (int i = 0; i < 7; ++i) {
        const int c = base + i;
        if (c < NCELLS) {
            cellStart[c] = excl + local[i];
            cellCursor[c] = excl + local[i];
        }
    }
    if (t == 255) cellStart[NCELLS] = part[255];
}

__global__ __launch_bounds__(256) void scatter_kernel(const float* __restrict__ coords,
                                                      const float* __restrict__ logits,
                                                      int* __restrict__ cellCursor,
                                                      float4* __restrict__ sortedPts,
                                                      int* __restrict__ orig,
                                                      float* __restrict__ ls) {
    const int p = blockIdx.x * blockDim.x + threadIdx.x;
    if (p >= N_PTS) return;
    const float x = coords[3 * p + 0];
    const float y = coords[3 * p + 1];
    const float z = coords[3 * p + 2];
    const int c = (cell1d(z) * GRID + cell1d(y)) * GRID + cell1d(x);
    const int pos = atomicAdd(&cellCursor[c], 1);
    sortedPts[pos] = make_float4(x, y, z, __uint_as_float((unsigned)p));
    orig[pos] = p;
    const float4* l4 = (const float4*)(logits + p * NCLS);
    float4* d4 = (float4*)(ls + pos * NCLS);
#pragma unroll
    for (int t = 0; t < 5; ++t) d4[t] = l4[t];
}

// ---------------------------------------------------------------------------
// Fast kNN: one wave per cell. Stage the 3^3 block's candidates in LDS once,
// then per point: filter d2<tau (tau <= h^2 => coverage exact) into keys,
// rank-by-broadcast select top-16. Edge/corner cells and undercounts -> fail
// list for the generic slow kernel. Neighbor indices are SORTED positions.
// ---------------------------------------------------------------------------
__global__ __launch_bounds__(256) void knn_fast_kernel(const float4* __restrict__ sortedPts,
                                                       const int* __restrict__ cellStart,
                                                       int* __restrict__ knn_out,
                                                       int* __restrict__ failList,
                                                       int* __restrict__ failCount) {
    __shared__ float4 cand[4][CAND_CAP];              // 32 KB
    __shared__ unsigned long long keys[4][KEY_CAP];   // 4 KB
    const int lane = threadIdx.x & 63;
    const int wave = threadIdx.x >> 6;
    const int c = blockIdx.x * 4 + wave;              // 432*4 = 1728 cells
    const int cz = c / (GRID * GRID);
    const int cy = (c / GRID) % GRID;
    const int cx = c % GRID;
    const int pbeg = cellStart[c];
    const int pend = cellStart[c + 1];
    const int npts = pend - pbeg;
    if (npts <= 0) return;
    const int bd = (cx == 0 || cx == GRID - 1) + (cy == 0 || cy == GRID - 1) +
                   (cz == 0 || cz == GRID - 1);
    const unsigned long long laneLt = (1ull << lane) - 1ull;

    bool bail = (bd >= 2);    // edge/corner cells: <16 pts within h for most points
    int nc = 0, ownOff = 0;
    if (!bail) {
        const int xlo = max(cx - 1, 0), xhi = min(cx + 1, GRID - 1);
#pragma unroll
        for (int dz = -1; dz <= 1; ++dz) {
#pragma unroll
            for (int dy = -1; dy <= 1; ++dy) {
                const int zz = cz + dz, yy = cy + dy;
                if ((unsigned)zz >= (unsigned)GRID || (unsigned)yy >= (unsigned)GRID)
                    continue;
                const int rowc = (zz * GRID + yy) * GRID;
                const int beg = cellStart[rowc + xlo];
                const int end = cellStart[rowc + xhi + 1];
                if (dz == 0 && dy == 0) ownOff = nc + (pbeg - beg);
                const int len = end - beg;
                for (int off = lane; off < len; off += 64) {
                    float4 pt = sortedPts[beg + off];
                    pt.w = __uint_as_float((unsigned)(beg + off));  // sorted pos
                    if (nc + off < CAND_CAP) cand[wave][nc + off] = pt;
                }
                nc += len;
            }
        }
        if (nc > CAND_CAP) bail = true;
    }
    if (bail) {
        int base = 0;
        if (lane == 0) base = atomicAdd(failCount, npts);
        base = __shfl(base, 0);
        for (int i = lane; i < npts; i += 64) failList[base + i] = pbeg + i;
        return;
    }

    for (int s = pbeg; s < pend; ++s) {
        const float4 qp = cand[wave][ownOff + (s - pbeg)];   // LDS broadcast
        // boundary-corrected tau targeting E[cnt]~26, capped at coverage h
        float r = R_TARGET;
        const float inv2r = 0.5f / r;
        const float fx = (fminf(qp.x + r, 1.f) - fmaxf(qp.x - r, 0.f)) * inv2r;
        const float fy = (fminf(qp.y + r, 1.f) - fmaxf(qp.y - r, 0.f)) * inv2r;
        const float fz = (fminf(qp.z + r, 1.f) - fmaxf(qp.z - r, 0.f)) * inv2r;
        const float f = fmaxf(fx * fy * fz, 0.05f);
        r = R_TARGET * __powf(f, -0.33333334f);
        r = fminf(r, 0.9995f * HCELL);
        float tau = r * r;

        int cnt = 0;
        bool ok = false;
        for (int att = 0; att < 4 && !ok; ++att) {
            cnt = 0;
            for (int j0 = 0; j0 < nc; j0 += 64) {
                const int j = j0 + lane;
                float4 pt = make_float4(0.f, 0.f, 0.f, 0.f);
                float d2 = 1e30f;
                if (j < nc) {
                    pt = cand[wave][j];
                    const float dx = pt.x - qp.x;
                    const float dy = pt.y - qp.y;
                    const float dz = pt.z - qp.z;
                    d2 = dx * dx + dy * dy + dz * dz;
                }
                const bool take = d2 < tau;
                const unsigned long long mm = __ballot(take);
                if (take) {
                    const int pos = cnt + (int)__popcll(mm & laneLt);
                    if (pos < KEY_CAP)
                        keys[wave][pos] =
                            (((unsigned long long)__float_as_uint(d2)) << 32) |
                            (unsigned long long)(unsigned)__float_as_uint(pt.w);
                }
                cnt += (int)__popcll(mm);
            }
            if (cnt >= KNN && cnt <= KEY_CAP) {
                ok = true;
            } else if (cnt < KNN) {
                if (tau >= TAU2MAX * 0.999f) break;   // coverage-limited -> slow path
                tau = TAU2MAX;
            } else {
                tau *= 0.6f;
            }
        }
        if (!ok) {
            if (lane == 0) { const int b = atomicAdd(failCount, 1); failList[b] = s; }
            continue;
        }
        // rank-by-broadcast: rank = #{keys < mine}; unique keys => ranks distinct
        const int m = cnt;
        const unsigned long long k0 = (lane < m) ? keys[wave][lane] : ~0ull;
        const unsigned long long k1 = (lane + 64 < m) ? keys[wave][lane + 64] : ~0ull;
        int r0 = 0, r1 = 0;
        for (int j2 = 0; j2 < m; ++j2) {
            const unsigned long long kj = keys[wave][j2];   // broadcast read
            r0 += (kj < k0);
            r1 += (kj < k1);
        }
        if (lane < m && r0 < KNN)
            knn_out[s * KNN + r0] = (int)(unsigned)(k0 & 0xffffffffull);
        if (lane + 64 < m && r1 < KNN)
            knn_out[s * KNN + r1] = (int)(unsigned)(k1 & 0xffffffffull);
    }
}

// ---------------------------------------------------------------------------
// Slow kNN: generic per-point ladder (hw=2,3,...) for fail-list points (~8%).
// ---------------------------------------------------------------------------
__global__ __launch_bounds__(256) void knn_slow_kernel(const float4* __restrict__ sortedPts,
                                                       const int* __restrict__ cellStart,
                                                       const int* __restrict__ failList,
                                                       const int* __restrict__ failCount,
                                                       int* __restrict__ knn_out) {
    __shared__ unsigned long long keys[4][KEY_CAP];
    const int lane = threadIdx.x & 63;
    const int wave = threadIdx.x >> 6;
    const int wid = blockIdx.x * 4 + wave;
    const int nw = gridDim.x * 4;
    const int nf = failCount[0];
    const unsigned long long laneLt = (1ull << lane) - 1ull;

    for (int fi = wid; fi < nf; fi += nw) {
        const int s = failList[fi];
        const float4 qp = sortedPts[s];
        const int cx = cell1d(qp.x), cy = cell1d(qp.y), cz = cell1d(qp.z);
        int hw = 2;
        float g = 0.9995f * 2.f * HCELL;
        float tau = g * g;
        int cnt = 0;
        for (int att = 0; att < 16; ++att) {
            cnt = 0;
            const int xlo = max(cx - hw, 0), xhi = min(cx + hw, GRID - 1);
            const int ylo = max(cy - hw, 0), yhi = min(cy + hw, GRID - 1);
            const int zlo = max(cz - hw, 0), zhi = min(cz + hw, GRID - 1);
            for (int zz = zlo; zz <= zhi; ++zz) {
                for (int yy = ylo; yy <= yhi; ++yy) {
                    const int rowc = (zz * GRID + yy) * GRID;
                    const int beg = cellStart[rowc + xlo];
                    const int end = cellStart[rowc + xhi + 1];
                    for (int j0 = beg; j0 < end; j0 += 64) {
                        const int j = j0 + lane;
                        const bool jv = j < end;
                        const float4 pt = sortedPts[jv ? j : beg];
                        const float dx = pt.x - qp.x;
                        const float dy = pt.y - qp.y;
                        const float dz = pt.z - qp.z;
                        const float d2 = dx * dx + dy * dy + dz * dz;
                        const bool take = jv && (d2 < tau);
                        const unsigned long long mm = __ballot(take);
                        if (take) {
                            const int pos = cnt + (int)__popcll(mm & laneLt);
                            if (pos < KEY_CAP)
                                keys[wave][pos] =
                                    (((unsigned long long)__float_as_uint(d2)) << 32) |
                                    (unsigned long long)(unsigned)j;
                        }
                        cnt += (int)__popcll(mm);
                    }
                }
            }
            if (cnt >= KNN && cnt <= KEY_CAP) break;
            if (cnt < KNN) {
                if (hw < GRID - 1) { ++hw; g = 0.9995f * (float)hw * HCELL; tau = g * g; }
                else tau *= 2.5f;
            } else {
                tau *= 0.6f;
            }
        }
        const int m = min(cnt, KEY_CAP);
        const unsigned long long k0 = (lane < m) ? keys[wave][lane] : ~0ull;
        const unsigned long long k1 = (lane + 64 < m) ? keys[wave][lane + 64] : ~0ull;
        int r0 = 0, r1 = 0;
        for (int j2 = 0; j2 < m; ++j2) {
            const unsigned long long kj = keys[wave][j2];
            r0 += (kj < k0);
            r1 += (kj < k1);
        }
        if (lane < m && r0 < KNN)
            knn_out[s * KNN + r0] = (int)(unsigned)(k0 & 0xffffffffull);
        if (lane + 64 < m && r1 < KNN)
            knn_out[s * KNN + r1] = (int)(unsigned)(k1 & 0xffffffffull);
    }
}

// ---------------------------------------------------------------------------
// Row softmax (sorted space): ls -> q0
// ---------------------------------------------------------------------------
__global__ __launch_bounds__(256) void softmax_kernel(const float* __restrict__ x,
                                                      float* __restrict__ q) {
    const int p = blockIdx.x * blockDim.x + threadIdx.x;
    if (p >= N_PTS) return;
    const float4* x4 = (const float4*)(x + p * NCLS);
    float v[NCLS];
#pragma unroll
    for (int t = 0; t < 5; ++t) {
        const float4 a = x4[t];
        v[4 * t + 0] = a.x; v[4 * t + 1] = a.y;
        v[4 * t + 2] = a.z; v[4 * t + 3] = a.w;
    }
    float mx = v[0];
#pragma unroll
    for (int c = 1; c < NCLS; ++c) mx = fmaxf(mx, v[c]);
    float sum = 0.f;
#pragma unroll
    for (int c = 0; c < NCLS; ++c) { v[c] = __expf(v[c] - mx); sum += v[c]; }
    const float inv = 1.f / sum;
    float4* q4 = (float4*)(q + p * NCLS);
#pragma unroll
    for (int t = 0; t < 5; ++t) {
        float4 a;
        a.x = v[4 * t + 0] * inv; a.y = v[4 * t + 1] * inv;
        a.z = v[4 * t + 2] * inv; a.w = v[4 * t + 3] * inv;
        q4[t] = a;
    }
}

// ---------------------------------------------------------------------------
// One CRF iteration in SORTED space (neighbor gathers are spatially local).
// 2 lanes per point. Final pass (outRef != nullptr) scatters to original order.
// ---------------------------------------------------------------------------
__global__ __launch_bounds__(256) void crf_iter_kernel(const float* __restrict__ ls,
                                                       const float* __restrict__ W,
                                                       const int* __restrict__ knn,
                                                       const float* __restrict__ qin,
                                                       float* __restrict__ qout,
                                                       const int* __restrict__ orig,
                                                       float* __restrict__ outRef,
                                                       float* __restrict__ outQ) {
    __shared__ float Ws[NCLS * NCLS];
    for (int i = threadIdx.x; i < NCLS * NCLS; i += blockDim.x) Ws[i] = W[i];
    __syncthreads();
    const int t = blockIdx.x * blockDim.x + threadIdx.x;
    const int p = t >> 1;
    const int half = t & 1;
    if (p >= N_PTS) return;

    float acc[NCLS];
#pragma unroll
    for (int c = 0; c < NCLS; ++c) acc[c] = 0.f;

    const int4* kn = (const int4*)(knn + p * KNN + half * 8);
#pragma unroll
    for (int g = 0; g < 2; ++g) {
        const int4 k4 = kn[g];
        const int ids[4] = {k4.x, k4.y, k4.z, k4.w};
#pragma unroll
        for (int u = 0; u < 4; ++u) {
            unsigned id = (unsigned)ids[u];
            if (id >= N_PTS) id = 0;     // safety clamp (unreachable)
            const float4* r4 = (const float4*)(qin + id * NCLS);
#pragma unroll
            for (int v = 0; v < 5; ++v) {
                const float4 a = r4[v];
                acc[4 * v + 0] += a.x; acc[4 * v + 1] += a.y;
                acc[4 * v + 2] += a.z; acc[4 * v + 3] += a.w;
            }
        }
    }
#pragma unroll
    for (int c = 0; c < NCLS; ++c) acc[c] += __shfl_xor(acc[c], 1, 64);

    float msg[NCLS];
#pragma unroll
    for (int c = 0; c < NCLS; ++c) msg[c] = acc[c] * (1.f / 16.f);

    float lg[NCLS];
    const float4* l4 = (const float4*)(ls + p * NCLS);
#pragma unroll
    for (int u = 0; u < 5; ++u) {
        const float4 a = l4[u];
        lg[4 * u + 0] = a.x; lg[4 * u + 1] = a.y;
        lg[4 * u + 2] = a.z; lg[4 * u + 3] = a.w;
    }

    float ref[NCLS];
#pragma unroll
    for (int c = 0; c < NCLS; ++c) {
        float s = lg[c];
#pragma unroll
        for (int k = 0; k < NCLS; ++k) s += msg[k] * Ws[c * NCLS + k];  // x @ W^T
        ref[c] = s;
    }

    const int o = (outRef != nullptr) ? orig[p] : p;

    if (outRef != nullptr && half == 0) {
        float4* r4 = (float4*)(outRef + o * NCLS);
#pragma unroll
        for (int u = 0; u < 5; ++u) {
            float4 a;
            a.x = ref[4 * u + 0]; a.y = ref[4 * u + 1];
            a.z = ref[4 * u + 2]; a.w = ref[4 * u + 3];
            r4[u] = a;
        }
    }

    float mx = ref[0];
#pragma unroll
    for (int c = 1; c < NCLS; ++c) mx = fmaxf(mx, ref[c]);
    float sum = 0.f;
    float ex[NCLS];
#pragma unroll
    for (int c = 0; c < NCLS; ++c) { ex[c] = __expf(ref[c] - mx); sum += ex[c]; }
    const float inv = 1.f / sum;
    if (half == 1) {
        float* dst = (outRef != nullptr) ? (outQ + o * NCLS) : (qout + p * NCLS);
        float4* q4 = (float4*)dst;
#pragma unroll
        for (int u = 0; u < 5; ++u) {
            float4 a;
            a.x = ex[4 * u + 0] * inv; a.y = ex[4 * u + 1] * inv;
            a.z = ex[4 * u + 2] * inv; a.w = ex[4 * u + 3] * inv;
            q4[u] = a;
        }
    }
}

// ---------------------------------------------------------------------------
extern "C" void kernel_launch(void* const* d_in, const int* in_sizes, int n_in,
                              void* d_out, int out_size, void* d_ws, size_t ws_size,
                              hipStream_t stream) {
    const float* logits = (const float*)d_in[0];   // (20000, 20)
    const float* coords = (const float*)d_in[1];   // (20000, 3)
    const float* W      = (const float*)d_in[2];   // (20, 20)
    float* out = (float*)d_out;                    // refined (400000) | q (400000)

    // workspace layout (~5 MB); q1s aliases the out q-region (safe: final pass
    // reads only q0s/ls and overwrites that region last).
    char* ws = (char*)d_ws;
    size_t off = 0;
    int* knn = (int*)(ws + off);              off += (size_t)N_PTS * KNN * 4;
    off = (off + 255) & ~(size_t)255;
    float* ls = (float*)(ws + off);           off += (size_t)N_PTS * NCLS * 4;
    off = (off + 255) & ~(size_t)255;
    float* q0s = (float*)(ws + off);          off += (size_t)N_PTS * NCLS * 4;
    off = (off + 255) & ~(size_t)255;
    float4* sortedPts = (float4*)(ws + off);  off += (size_t)N_PTS * 16;
    off = (off + 255) & ~(size_t)255;
    int* orig = (int*)(ws + off);             off += (size_t)N_PTS * 4;
    off = (off + 255) & ~(size_t)255;
    int* failList = (int*)(ws + off);         off += (size_t)N_PTS * 4;
    off = (off + 255) & ~(size_t)255;
    int* cellCount = (int*)(ws + off);        off += (size_t)(NCELLS + 1) * 4;
    int* failCount = cellCount + NCELLS;      // zeroed together with cellCount
    off = (off + 255) & ~(size_t)255;
    int* cellStart = (int*)(ws + off);        off += (size_t)(NCELLS + 1) * 4;
    int* cellCursor = (int*)(ws + off);
    float* q1s = out + N_PTS * NCLS;          // scratch in out's q region

    const int threads = 256;
    const int pblocks = (N_PTS + threads - 1) / threads;

    hipMemsetAsync(cellCount, 0, (NCELLS + 1) * sizeof(int), stream);
    count_kernel<<<pblocks, threads, 0, stream>>>(coords, cellCount);
    scan_kernel<<<1, threads, 0, stream>>>(cellCount, cellStart, cellCursor);
    scatter_kernel<<<pblocks, threads, 0, stream>>>(coords, logits, cellCursor,
                                                    sortedPts, orig, ls);
    knn_fast_kernel<<<NCELLS / 4, threads, 0, stream>>>(sortedPts, cellStart, knn,
                                                        failList, failCount);
    knn_slow_kernel<<<256, threads, 0, stream>>>(sortedPts, cellStart, failList,
                                                 failCount, knn);
    softmax_kernel<<<pblocks, threads, 0, stream>>>(ls, q0s);

    const int cblocks = (2 * N_PTS + threads - 1) / threads;
    crf_iter_kernel<<<cblocks, threads, 0, stream>>>(ls, W, knn, q0s, q1s, orig,
                                                     nullptr, nullptr);
    crf_iter_kernel<<<cblocks, threads, 0, stream>>>(ls, W, knn, q1s, q0s, orig,
                                                     nullptr, nullptr);
    crf_iter_kernel<<<cblocks, threads, 0, stream>>>(ls, W, knn, q0s, nullptr, orig,
                                                     out, out + N_PTS * NCLS);
}

// Round 4
// 136.497 us; speedup vs baseline: 1.5078x; 1.5078x over previous
//
#include <hip/hip_runtime.h>

#define N_PTS 20000
#define NCLS 20
#define KNN 16
#define GRID 12
#define NCELLS (GRID * GRID * GRID)
#define HCELL (1.0f / (float)GRID)
#define CAND_CAP 1152      // worst staged block: 75 cells * 11.6 = 868 + 6 sigma
#define KEY_CAP 192        // filtered keys per point (E~26)
#define R_TARGET 0.0680f   // radius giving E[cnt]~26 in the interior

__device__ __forceinline__ int cell1d(float v) {
    int c = (int)(v * (float)GRID);
    return min(max(c, 0), GRID - 1);
}

// ---------------------------------------------------------------------------
// Build: histogram + exclusive scan in ONE single-block kernel (no memset).
// ---------------------------------------------------------------------------
__global__ __launch_bounds__(1024) void build_kernel(const float* __restrict__ coords,
                                                     int* __restrict__ cellStart,
                                                     int* __restrict__ cellCursor) {
    __shared__ int hist[NCELLS];     // 6.75 KB
    __shared__ int part[1024];       // 4 KB
    const int t = threadIdx.x;
    for (int c = t; c < NCELLS; c += 1024) hist[c] = 0;
    __syncthreads();
    for (int p = t; p < N_PTS; p += 1024) {
        const int cx = cell1d(coords[3 * p + 0]);
        const int cy = cell1d(coords[3 * p + 1]);
        const int cz = cell1d(coords[3 * p + 2]);
        atomicAdd(&hist[(cz * GRID + cy) * GRID + cx], 1);
    }
    __syncthreads();
    const int c0 = 2 * t, c1 = 2 * t + 1;
    const int v0 = (c0 < NCELLS) ? hist[c0] : 0;
    const int v1 = (c1 < NCELLS) ? hist[c1] : 0;
    part[t] = v0 + v1;
    __syncthreads();
    for (int off = 1; off < 1024; off <<= 1) {
        const int v = part[t] + ((t >= off) ? part[t - off] : 0);
        __syncthreads();
        part[t] = v;
        __syncthreads();
    }
    const int excl = (t > 0) ? part[t - 1] : 0;
    if (c0 < NCELLS) { cellStart[c0] = excl;      cellCursor[c0] = excl; }
    if (c1 < NCELLS) { cellStart[c1] = excl + v0; cellCursor[c1] = excl + v0; }
    if (t == 1023) cellStart[NCELLS] = part[1023];
}

// ---------------------------------------------------------------------------
// Scatter (counting sort) + gather logits row + FUSED softmax -> q0s, ls.
// ---------------------------------------------------------------------------
__global__ __launch_bounds__(256) void scatter_kernel(const float* __restrict__ coords,
                                                      const float* __restrict__ logits,
                                                      int* __restrict__ cellCursor,
                                                      float4* __restrict__ sortedPts,
                                                      int* __restrict__ orig,
                                                      float* __restrict__ ls,
                                                      float* __restrict__ q0s) {
    const int p = blockIdx.x * blockDim.x + threadIdx.x;
    if (p >= N_PTS) return;
    const float x = coords[3 * p + 0];
    const float y = coords[3 * p + 1];
    const float z = coords[3 * p + 2];
    const int c = (cell1d(z) * GRID + cell1d(y)) * GRID + cell1d(x);
    const int pos = atomicAdd(&cellCursor[c], 1);
    sortedPts[pos] = make_float4(x, y, z, __uint_as_float((unsigned)p));
    orig[pos] = p;
    const float4* l4 = (const float4*)(logits + p * NCLS);
    float v[NCLS];
#pragma unroll
    for (int u = 0; u < 5; ++u) {
        const float4 a = l4[u];
        v[4 * u + 0] = a.x; v[4 * u + 1] = a.y;
        v[4 * u + 2] = a.z; v[4 * u + 3] = a.w;
    }
    float4* d4 = (float4*)(ls + pos * NCLS);
#pragma unroll
    for (int u = 0; u < 5; ++u)
        d4[u] = make_float4(v[4 * u], v[4 * u + 1], v[4 * u + 2], v[4 * u + 3]);
    float mx = v[0];
#pragma unroll
    for (int cc = 1; cc < NCLS; ++cc) mx = fmaxf(mx, v[cc]);
    float sum = 0.f;
#pragma unroll
    for (int cc = 0; cc < NCLS; ++cc) { v[cc] = __expf(v[cc] - mx); sum += v[cc]; }
    const float inv = 1.f / sum;
    float4* q4 = (float4*)(q0s + pos * NCLS);
#pragma unroll
    for (int u = 0; u < 5; ++u)
        q4[u] = make_float4(v[4 * u] * inv, v[4 * u + 1] * inv,
                            v[4 * u + 2] * inv, v[4 * u + 3] * inv);
}

// ---------------------------------------------------------------------------
// Rare exact fallback: wave-cooperative global-memory ladder (hw growing).
// ---------------------------------------------------------------------------
__device__ void knn_ladder(const float4* __restrict__ sortedPts,
                           const int* __restrict__ cellStart,
                           const float4 qp, const int s, int hw,
                           unsigned long long* keys, const int lane,
                           int* __restrict__ knn_out) {
    const unsigned long long laneLt = (1ull << lane) - 1ull;
    const int cx = cell1d(qp.x), cy = cell1d(qp.y), cz = cell1d(qp.z);
    float g = 0.9995f * (float)hw * HCELL;
    float tau = g * g;
    int cnt = 0;
    for (int att = 0; att < 16; ++att) {
        cnt = 0;
        const int xlo = max(cx - hw, 0), xhi = min(cx + hw, GRID - 1);
        const int ylo = max(cy - hw, 0), yhi = min(cy + hw, GRID - 1);
        const int zlo = max(cz - hw, 0), zhi = min(cz + hw, GRID - 1);
        for (int zz = zlo; zz <= zhi; ++zz) {
            for (int yy = ylo; yy <= yhi; ++yy) {
                const int rowc = (zz * GRID + yy) * GRID;
                const int beg = cellStart[rowc + xlo];
                const int end = cellStart[rowc + xhi + 1];
                for (int j0 = beg; j0 < end; j0 += 64) {
                    const int j = j0 + lane;
                    const bool jv = j < end;
                    const float4 pt = sortedPts[jv ? j : beg];
                    const float dx = pt.x - qp.x, dy = pt.y - qp.y, dz = pt.z - qp.z;
                    const float d2 = dx * dx + dy * dy + dz * dz;
                    const bool take = jv && (d2 < tau);
                    const unsigned long long mm = __ballot(take);
                    if (take) {
                        const int pos = cnt + (int)__popcll(mm & laneLt);
                        if (pos < KEY_CAP)
                            keys[pos] = (((unsigned long long)__float_as_uint(d2)) << 32) |
                                        (unsigned long long)(unsigned)j;
                    }
                    cnt += (int)__popcll(mm);
                }
            }
        }
        if (cnt >= KNN && cnt <= KEY_CAP) break;
        if (cnt < KNN) {
            if (hw < GRID - 1) { ++hw; g = 0.9995f * (float)hw * HCELL; tau = g * g; }
            else tau *= 2.5f;
        } else {
            tau *= 0.6f;
        }
    }
    const int m = min(cnt, KEY_CAP);
    const unsigned long long k0 = (lane < m) ? keys[lane] : ~0ull;
    const unsigned long long k1 = (lane + 64 < m) ? keys[lane + 64] : ~0ull;
    const unsigned long long k2 = (lane + 128 < m) ? keys[lane + 128] : ~0ull;
    int r0 = 0, r1 = 0, r2 = 0;
    for (int j = 0; j < m; ++j) {
        const unsigned long long kj = keys[j];
        r0 += (kj < k0); r1 += (kj < k1); r2 += (kj < k2);
    }
    if (lane < m && r0 < KNN)       knn_out[s * KNN + r0] = (int)(unsigned)(k0 & 0xffffffffull);
    if (lane + 64 < m && r1 < KNN)  knn_out[s * KNN + r1] = (int)(unsigned)(k1 & 0xffffffffull);
    if (lane + 128 < m && r2 < KNN) knn_out[s * KNN + r2] = (int)(unsigned)(k2 & 0xffffffffull);
}

// ---------------------------------------------------------------------------
// kNN: ONE BLOCK per cell (1728 blocks, 4 waves). Block stages the clipped
// (2*hs+1)^3 candidate region in LDS once (hs=1 interior, hs=2 boundary ->
// coverage 2h >= corner r16); waves split the cell's points. Per point:
// filter d2<tau into keys, rank-by-broadcast top-16. Exact on accept.
// ---------------------------------------------------------------------------
__global__ __launch_bounds__(256) void knn_kernel(const float4* __restrict__ sortedPts,
                                                  const int* __restrict__ cellStart,
                                                  int* __restrict__ knn_out) {
    __shared__ float4 cand[CAND_CAP];                 // 18 KB
    __shared__ unsigned long long keys[4][KEY_CAP];   // 6 KB
    const int lane = threadIdx.x & 63;
    const int wave = threadIdx.x >> 6;
    const int c = blockIdx.x;
    const int cz = c / (GRID * GRID);
    const int cy = (c / GRID) % GRID;
    const int cx = c % GRID;
    const int pbeg = cellStart[c];
    const int pend = cellStart[c + 1];
    const int npts = pend - pbeg;
    if (npts <= 0) return;
    const int bd = (cx == 0 || cx == GRID - 1) + (cy == 0 || cy == GRID - 1) +
                   (cz == 0 || cz == GRID - 1);
    const int hs = bd ? 2 : 1;
    const unsigned long long laneLt = (1ull << lane) - 1ull;

    const int xlo = max(cx - hs, 0), xhi = min(cx + hs, GRID - 1);
    const int ylo = max(cy - hs, 0), yhi = min(cy + hs, GRID - 1);
    const int zlo = max(cz - hs, 0), zhi = min(cz + hs, GRID - 1);
    const int ny = yhi - ylo + 1;
    const int nruns = (zhi - zlo + 1) * ny;           // <= 25 runs (x-contiguous)

    // lane-parallel run metadata + wave prefix scan (redundant per wave)
    int beg = 0, len = 0;
    if (lane < nruns) {
        const int zz = zlo + lane / ny;
        const int yy = ylo + lane % ny;
        const int rowc = (zz * GRID + yy) * GRID;
        beg = cellStart[rowc + xlo];
        len = cellStart[rowc + xhi + 1] - beg;
    }
    int off = len;
#pragma unroll
    for (int sh = 1; sh < 64; sh <<= 1) {
        const int o = __shfl_up(off, sh, 64);
        if (lane >= sh) off += o;
    }
    const int nc = __shfl(off, 63);
    off -= len;                                        // exclusive
    const int ownRun = (cz - zlo) * ny + (cy - ylo);
    const int ownOff = __shfl(off, ownRun) + (pbeg - __shfl(beg, ownRun));

    // stage: wave w handles runs w, w+4, ...
    if (nc <= CAND_CAP) {
        for (int r = wave; r < nruns; r += 4) {
            const int rb = __shfl(beg, r);
            const int rl = __shfl(len, r);
            const int ro = __shfl(off, r);
            for (int i = lane; i < rl; i += 64) {
                float4 pt = sortedPts[rb + i];
                pt.w = __uint_as_float((unsigned)(rb + i));
                cand[ro + i] = pt;
            }
        }
    }
    __syncthreads();

    if (nc > CAND_CAP) {                               // ~never (6-sigma)
        for (int idx = wave; idx < npts; idx += 4)
            knn_ladder(sortedPts, cellStart, sortedPts[pbeg + idx], pbeg + idx,
                       hs + 1, keys[wave], lane, knn_out);
        return;
    }

    const float taumaxr = 0.9995f * (float)hs * HCELL;
    const float taumax = taumaxr * taumaxr;

    for (int idx = wave; idx < npts; idx += 4) {
        const int s = pbeg + idx;
        const float4 qp = cand[ownOff + idx];
        // boundary-corrected tau targeting E[cnt]~26, capped at coverage hs*h
        float r = R_TARGET;
        const float inv2r = 0.5f / r;
        const float fx = (fminf(qp.x + r, 1.f) - fmaxf(qp.x - r, 0.f)) * inv2r;
        const float fy = (fminf(qp.y + r, 1.f) - fmaxf(qp.y - r, 0.f)) * inv2r;
        const float fz = (fminf(qp.z + r, 1.f) - fmaxf(qp.z - r, 0.f)) * inv2r;
        const float f = fmaxf(fx * fy * fz, 0.05f);
        r = R_TARGET * __powf(f, -0.33333334f);
        float tau = fminf(r * r, taumax);
        bool triedMax = (tau >= taumax * 0.999f);

        int cnt = 0;
        bool ok = false;
        for (int att = 0; att < 6 && !ok; ++att) {
            cnt = 0;
            for (int j0 = 0; j0 < nc; j0 += 64) {
                const int j = j0 + lane;
                float d2 = 1e30f;
                unsigned pw = 0;
                if (j < nc) {
                    const float4 pt = cand[j];
                    const float dx = pt.x - qp.x, dy = pt.y - qp.y, dz = pt.z - qp.z;
                    d2 = dx * dx + dy * dy + dz * dz;
                    pw = __float_as_uint(pt.w);
                }
                const bool take = d2 < tau;
                const unsigned long long mm = __ballot(take);
                if (take) {
                    const int pos = cnt + (int)__popcll(mm & laneLt);
                    if (pos < KEY_CAP)
                        keys[wave][pos] =
                            (((unsigned long long)__float_as_uint(d2)) << 32) |
                            (unsigned long long)pw;
                }
                cnt += (int)__popcll(mm);
            }
            if (cnt >= KNN && cnt <= KEY_CAP) ok = true;
            else if (cnt < KNN) {
                if (triedMax) break;
                tau = taumax; triedMax = true;
            } else tau *= 0.6f;
        }
        if (!ok) {                                     // ~never
            knn_ladder(sortedPts, cellStart, qp, s, hs + 1, keys[wave], lane, knn_out);
            continue;
        }
        const int m = cnt;
        const unsigned long long k0 = (lane < m) ? keys[wave][lane] : ~0ull;
        const unsigned long long k1 = (lane + 64 < m) ? keys[wave][lane + 64] : ~0ull;
        const unsigned long long k2 = (lane + 128 < m) ? keys[wave][lane + 128] : ~0ull;
        int r0 = 0, r1 = 0, r2 = 0;
        for (int j = 0; j < m; ++j) {
            const unsigned long long kj = keys[wave][j];   // LDS broadcast
            r0 += (kj < k0); r1 += (kj < k1); r2 += (kj < k2);
        }
        if (lane < m && r0 < KNN)       knn_out[s * KNN + r0] = (int)(unsigned)(k0 & 0xffffffffull);
        if (lane + 64 < m && r1 < KNN)  knn_out[s * KNN + r1] = (int)(unsigned)(k1 & 0xffffffffull);
        if (lane + 128 < m && r2 < KNN) knn_out[s * KNN + r2] = (int)(unsigned)(k2 & 0xffffffffull);
    }
}

// ---------------------------------------------------------------------------
// CRF iteration, SORTED space, 4 lanes/point: each lane gathers 4 neighbour
// rows, 2-round shfl merge, matvec distributed 5 classes/lane, softmax via
// shfl reductions. Final pass scatters refined+q to original order.
// ---------------------------------------------------------------------------
__global__ __launch_bounds__(256) void crf_iter_kernel(const float* __restrict__ ls,
                                                       const float* __restrict__ W,
                                                       const int* __restrict__ knn,
                                                       const float* __restrict__ qin,
                                                       float* __restrict__ qout,
                                                       const int* __restrict__ orig,
                                                       float* __restrict__ outRef,
                                                       float* __restrict__ outQ) {
    __shared__ float Ws[NCLS * NCLS];
    for (int i = threadIdx.x; i < NCLS * NCLS; i += blockDim.x) Ws[i] = W[i];
    __syncthreads();
    const int t = blockIdx.x * blockDim.x + threadIdx.x;
    const int p = t >> 2;
    const int qtr = t & 3;
    if (p >= N_PTS) return;

    float acc[NCLS];
#pragma unroll
    for (int c = 0; c < NCLS; ++c) acc[c] = 0.f;

    const int4 k4 = ((const int4*)(knn + p * KNN))[qtr];
    const int ids[4] = {k4.x, k4.y, k4.z, k4.w};
#pragma unroll
    for (int u = 0; u < 4; ++u) {
        unsigned id = (unsigned)ids[u];
        if (id >= N_PTS) id = 0;        // safety clamp (unreachable)
        const float4* r4 = (const float4*)(qin + id * NCLS);
#pragma unroll
        for (int v = 0; v < 5; ++v) {
            const float4 a = r4[v];
            acc[4 * v + 0] += a.x; acc[4 * v + 1] += a.y;
            acc[4 * v + 2] += a.z; acc[4 * v + 3] += a.w;
        }
    }
#pragma unroll
    for (int c = 0; c < NCLS; ++c) {
        acc[c] += __shfl_xor(acc[c], 1, 64);
        acc[c] += __shfl_xor(acc[c], 2, 64);
        acc[c] *= (1.f / 16.f);          // msg
    }

    // my 5 classes
    const int c0 = qtr * 5;
    float ref[5];
#pragma unroll
    for (int i = 0; i < 5; ++i) {
        float s = ls[p * NCLS + c0 + i];
#pragma unroll
        for (int k = 0; k < NCLS; ++k) s += acc[k] * Ws[(c0 + i) * NCLS + k];  // x@W^T
        ref[i] = s;
    }

    float mx = ref[0];
#pragma unroll
    for (int i = 1; i < 5; ++i) mx = fmaxf(mx, ref[i]);
    mx = fmaxf(mx, __shfl_xor(mx, 1, 64));
    mx = fmaxf(mx, __shfl_xor(mx, 2, 64));
    float ex[5];
    float ps = 0.f;
#pragma unroll
    for (int i = 0; i < 5; ++i) { ex[i] = __expf(ref[i] - mx); ps += ex[i]; }
    ps += __shfl_xor(ps, 1, 64);
    ps += __shfl_xor(ps, 2, 64);
    const float inv = 1.f / ps;

    if (outRef != nullptr) {
        const int o = orig[p];
#pragma unroll
        for (int i = 0; i < 5; ++i) {
            outRef[o * NCLS + c0 + i] = ref[i];
            outQ[o * NCLS + c0 + i] = ex[i] * inv;
        }
    } else {
#pragma unroll
        for (int i = 0; i < 5; ++i) qout[p * NCLS + c0 + i] = ex[i] * inv;
    }
}

// ---------------------------------------------------------------------------
extern "C" void kernel_launch(void* const* d_in, const int* in_sizes, int n_in,
                              void* d_out, int out_size, void* d_ws, size_t ws_size,
                              hipStream_t stream) {
    const float* logits = (const float*)d_in[0];   // (20000, 20)
    const float* coords = (const float*)d_in[1];   // (20000, 3)
    const float* W      = (const float*)d_in[2];   // (20, 20)
    float* out = (float*)d_out;                    // refined (400000) | q (400000)

    // workspace (~5 MB); q1s aliases out's q-region (safe: final pass reads
    // only q0s/ls/knn/orig and overwrites that region last).
    char* ws = (char*)d_ws;
    size_t off = 0;
    int* knn = (int*)(ws + off);              off += (size_t)N_PTS * KNN * 4;
    off = (off + 255) & ~(size_t)255;
    float* ls = (float*)(ws + off);           off += (size_t)N_PTS * NCLS * 4;
    off = (off + 255) & ~(size_t)255;
    float* q0s = (float*)(ws + off);          off += (size_t)N_PTS * NCLS * 4;
    off = (off + 255) & ~(size_t)255;
    float4* sortedPts = (float4*)(ws + off);  off += (size_t)N_PTS * 16;
    off = (off + 255) & ~(size_t)255;
    int* orig = (int*)(ws + off);             off += (size_t)N_PTS * 4;
    off = (off + 255) & ~(size_t)255;
    int* cellStart = (int*)(ws + off);        off += (size_t)(NCELLS + 1) * 4;
    off = (off + 255) & ~(size_t)255;
    int* cellCursor = (int*)(ws + off);
    float* q1s = out + N_PTS * NCLS;

    const int threads = 256;
    const int pblocks = (N_PTS + threads - 1) / threads;
    const int cblocks = (4 * N_PTS + threads - 1) / threads;

    build_kernel<<<1, 1024, 0, stream>>>(coords, cellStart, cellCursor);
    scatter_kernel<<<pblocks, threads, 0, stream>>>(coords, logits, cellCursor,
                                                    sortedPts, orig, ls, q0s);
    knn_kernel<<<NCELLS, threads, 0, stream>>>(sortedPts, cellStart, knn);
    crf_iter_kernel<<<cblocks, threads, 0, stream>>>(ls, W, knn, q0s, q1s, orig,
                                                     nullptr, nullptr);
    crf_iter_kernel<<<cblocks, threads, 0, stream>>>(ls, W, knn, q1s, q0s, orig,
                                                     nullptr, nullptr);
    crf_iter_kernel<<<cblocks, threads, 0, stream>>>(ls, W, knn, q0s, nullptr, orig,
                                                     out, out + N_PTS * NCLS);
}

// Round 5
// 129.654 us; speedup vs baseline: 1.5874x; 1.0528x over previous
//
#include <hip/hip_runtime.h>

#define N_PTS 20000
#define NCLS 20
#define KNN 16
#define GRID 12
#define NCELLS (GRID * GRID * GRID)
#define HCELL (1.0f / (float)GRID)
#define CAND_CAP 512       // 3^3 staged block: E~313 interior, +6 sigma < 512
#define KEY_CAP 128        // filtered keys per point (E~26, taumax E~49)
#define R_TARGET 0.0680f   // radius giving E[cnt]~26 in the interior

__device__ __forceinline__ int cell1d(float v) {
    int c = (int)(v * (float)GRID);
    return min(max(c, 0), GRID - 1);
}

// ---------------------------------------------------------------------------
// Count (grid-wide atomics) + fused scan: the last block to finish performs
// the 1728-cell exclusive scan (agent-scope loads; done-counter handshake).
// ---------------------------------------------------------------------------
__global__ __launch_bounds__(256) void count_scan_kernel(const float* __restrict__ coords,
                                                         int* __restrict__ cellCount,
                                                         int* __restrict__ doneCtr,
                                                         int* __restrict__ cellStart,
                                                         int* __restrict__ cellCursor) {
    const int p = blockIdx.x * blockDim.x + threadIdx.x;
    if (p < N_PTS) {
        const int cx = cell1d(coords[3 * p + 0]);
        const int cy = cell1d(coords[3 * p + 1]);
        const int cz = cell1d(coords[3 * p + 2]);
        atomicAdd(&cellCount[(cz * GRID + cy) * GRID + cx], 1);
    }
    __threadfence();
    __syncthreads();
    __shared__ bool isLast;
    if (threadIdx.x == 0)
        isLast = (atomicAdd(doneCtr, 1) == (int)gridDim.x - 1);
    __syncthreads();
    if (!isLast) return;

    // exclusive scan of 1728 counts by this one block (256 thr x 7)
    __shared__ int part[256];
    const int t = threadIdx.x;
    const int base = t * 7;                   // 256*7 = 1792 >= 1728
    int local[7];
    int s = 0;
#pragma unroll
    for (int i = 0; i < 7; ++i) {
        const int c = base + i;
        const int v = (c < NCELLS)
            ? __hip_atomic_load(&cellCount[c], __ATOMIC_RELAXED, __HIP_MEMORY_SCOPE_AGENT)
            : 0;
        local[i] = s;
        s += v;
    }
    part[t] = s;
    __syncthreads();
    for (int off = 1; off < 256; off <<= 1) {
        const int v = part[t] + ((t >= off) ? part[t - off] : 0);
        __syncthreads();
        part[t] = v;
        __syncthreads();
    }
    const int excl = (t > 0) ? part[t - 1] : 0;
#pragma unroll
    for (int i = 0; i < 7; ++i) {
        const int c = base + i;
        if (c < NCELLS) {
            cellStart[c] = excl + local[i];
            cellCursor[c] = excl + local[i];
        }
    }
    if (t == 255) cellStart[NCELLS] = part[255];
}

// ---------------------------------------------------------------------------
// Scatter (counting sort) + gather logits row + FUSED softmax -> q0s, ls.
// ---------------------------------------------------------------------------
__global__ __launch_bounds__(256) void scatter_kernel(const float* __restrict__ coords,
                                                      const float* __restrict__ logits,
                                                      int* __restrict__ cellCursor,
                                                      float4* __restrict__ sortedPts,
                                                      int* __restrict__ orig,
                                                      float* __restrict__ ls,
                                                      float* __restrict__ q0s) {
    const int p = blockIdx.x * blockDim.x + threadIdx.x;
    if (p >= N_PTS) return;
    const float x = coords[3 * p + 0];
    const float y = coords[3 * p + 1];
    const float z = coords[3 * p + 2];
    const int c = (cell1d(z) * GRID + cell1d(y)) * GRID + cell1d(x);
    const int pos = atomicAdd(&cellCursor[c], 1);
    sortedPts[pos] = make_float4(x, y, z, __uint_as_float((unsigned)p));
    orig[pos] = p;
    const float4* l4 = (const float4*)(logits + p * NCLS);
    float v[NCLS];
#pragma unroll
    for (int u = 0; u < 5; ++u) {
        const float4 a = l4[u];
        v[4 * u + 0] = a.x; v[4 * u + 1] = a.y;
        v[4 * u + 2] = a.z; v[4 * u + 3] = a.w;
    }
    float4* d4 = (float4*)(ls + pos * NCLS);
#pragma unroll
    for (int u = 0; u < 5; ++u)
        d4[u] = make_float4(v[4 * u], v[4 * u + 1], v[4 * u + 2], v[4 * u + 3]);
    float mx = v[0];
#pragma unroll
    for (int cc = 1; cc < NCLS; ++cc) mx = fmaxf(mx, v[cc]);
    float sum = 0.f;
#pragma unroll
    for (int cc = 0; cc < NCLS; ++cc) { v[cc] = __expf(v[cc] - mx); sum += v[cc]; }
    const float inv = 1.f / sum;
    float4* q4 = (float4*)(q0s + pos * NCLS);
#pragma unroll
    for (int u = 0; u < 5; ++u)
        q4[u] = make_float4(v[4 * u] * inv, v[4 * u + 1] * inv,
                            v[4 * u + 2] * inv, v[4 * u + 3] * inv);
}

// ---------------------------------------------------------------------------
// Rare exact fallback: wave-cooperative global-memory ladder (hw growing).
// ---------------------------------------------------------------------------
__device__ void knn_ladder(const float4* __restrict__ sortedPts,
                           const int* __restrict__ cellStart,
                           const float4 qp, const int s, int hw,
                           unsigned long long* keys, const int lane,
                           int* __restrict__ knn_out) {
    const unsigned long long laneLt = (1ull << lane) - 1ull;
    const int cx = cell1d(qp.x), cy = cell1d(qp.y), cz = cell1d(qp.z);
    float g = 0.9995f * (float)hw * HCELL;
    float tau = g * g;
    int cnt = 0;
    for (int att = 0; att < 16; ++att) {
        cnt = 0;
        const int xlo = max(cx - hw, 0), xhi = min(cx + hw, GRID - 1);
        const int ylo = max(cy - hw, 0), yhi = min(cy + hw, GRID - 1);
        const int zlo = max(cz - hw, 0), zhi = min(cz + hw, GRID - 1);
        for (int zz = zlo; zz <= zhi; ++zz) {
            for (int yy = ylo; yy <= yhi; ++yy) {
                const int rowc = (zz * GRID + yy) * GRID;
                const int beg = cellStart[rowc + xlo];
                const int end = cellStart[rowc + xhi + 1];
                for (int j0 = beg; j0 < end; j0 += 64) {
                    const int j = j0 + lane;
                    const bool jv = j < end;
                    const float4 pt = sortedPts[jv ? j : beg];
                    const float dx = pt.x - qp.x, dy = pt.y - qp.y, dz = pt.z - qp.z;
                    const float d2 = dx * dx + dy * dy + dz * dz;
                    const bool take = jv && (d2 < tau);
                    const unsigned long long mm = __ballot(take);
                    if (take) {
                        const int pos = cnt + (int)__popcll(mm & laneLt);
                        if (pos < KEY_CAP)
                            keys[pos] = (((unsigned long long)__float_as_uint(d2)) << 32) |
                                        (unsigned long long)(unsigned)j;
                    }
                    cnt += (int)__popcll(mm);
                }
            }
        }
        if (cnt >= KNN && cnt <= KEY_CAP) break;
        if (cnt < KNN) {
            if (hw < GRID - 1) { ++hw; g = 0.9995f * (float)hw * HCELL; tau = g * g; }
            else tau *= 2.5f;
        } else {
            tau *= 0.6f;
        }
    }
    const int m = min(cnt, KEY_CAP);
    const unsigned long long k0 = (lane < m) ? keys[lane] : ~0ull;
    const unsigned long long k1 = (lane + 64 < m) ? keys[lane + 64] : ~0ull;
    int r0 = 0, r1 = 0;
    for (int j = 0; j < m; ++j) {
        const unsigned long long kj = keys[j];
        r0 += (kj < k0); r1 += (kj < k1);
    }
    if (lane < m && r0 < KNN)      knn_out[s * KNN + r0] = (int)(unsigned)(k0 & 0xffffffffull);
    if (lane + 64 < m && r1 < KNN) knn_out[s * KNN + r1] = (int)(unsigned)(k1 & 0xffffffffull);
}

// ---------------------------------------------------------------------------
// kNN: TWO blocks per cell (3456 blocks, 4 waves, 12KB LDS -> 8 blocks/CU).
// Each block stages the clipped 3^3 candidate region once; its waves take the
// cell's points with idx%2==half, stride 8. Per point: analytic tau filter
// (capped at coverage h => exact on accept), rank-by-broadcast top-16;
// undercovered boundary points (~4%) use the inline global ladder (hw=2).
// ---------------------------------------------------------------------------
__global__ __launch_bounds__(256) void knn_kernel(const float4* __restrict__ sortedPts,
                                                  const int* __restrict__ cellStart,
                                                  int* __restrict__ knn_out) {
    __shared__ float4 cand[CAND_CAP];                 // 8 KB
    __shared__ unsigned long long keys[4][KEY_CAP];   // 4 KB
    const int lane = threadIdx.x & 63;
    const int wave = threadIdx.x >> 6;
    const int c = blockIdx.x >> 1;
    const int half = blockIdx.x & 1;
    const int cz = c / (GRID * GRID);
    const int cy = (c / GRID) % GRID;
    const int cx = c % GRID;
    const int pbeg = cellStart[c];
    const int pend = cellStart[c + 1];
    const int npts = pend - pbeg;
    if (npts <= 0) return;
    const unsigned long long laneLt = (1ull << lane) - 1ull;

    const int xlo = max(cx - 1, 0), xhi = min(cx + 1, GRID - 1);
    const int ylo = max(cy - 1, 0), yhi = min(cy + 1, GRID - 1);
    const int zlo = max(cz - 1, 0), zhi = min(cz + 1, GRID - 1);
    const int ny = yhi - ylo + 1;
    const int nruns = (zhi - zlo + 1) * ny;           // <= 9 x-contiguous runs

    int beg = 0, len = 0;
    if (lane < nruns) {
        const int zz = zlo + lane / ny;
        const int yy = ylo + lane % ny;
        const int rowc = (zz * GRID + yy) * GRID;
        beg = cellStart[rowc + xlo];
        len = cellStart[rowc + xhi + 1] - beg;
    }
    int off = len;
#pragma unroll
    for (int sh = 1; sh < 16; sh <<= 1) {
        const int o = __shfl_up(off, sh, 64);
        if (lane >= sh) off += o;
    }
    const int nc = __shfl(off, nruns - 1);
    off -= len;                                        // exclusive
    const int ownRun = (cz - zlo) * ny + (cy - ylo);
    const int ownOff = __shfl(off, ownRun) + (pbeg - __shfl(beg, ownRun));

    if (nc <= CAND_CAP) {
        for (int r = wave; r < nruns; r += 4) {
            const int rb = __shfl(beg, r);
            const int rl = __shfl(len, r);
            const int ro = __shfl(off, r);
            for (int i = lane; i < rl; i += 64) {
                float4 pt = sortedPts[rb + i];
                pt.w = __uint_as_float((unsigned)(rb + i));
                cand[ro + i] = pt;
            }
        }
    }
    __syncthreads();

    if (nc > CAND_CAP) {                               // ~never (6+ sigma)
        for (int idx = 2 * wave + half; idx < npts; idx += 8)
            knn_ladder(sortedPts, cellStart, sortedPts[pbeg + idx], pbeg + idx,
                       2, keys[wave], lane, knn_out);
        return;
    }

    const float taumaxr = 0.9995f * HCELL;
    const float taumax = taumaxr * taumaxr;

    for (int idx = 2 * wave + half; idx < npts; idx += 8) {
        const int s = pbeg + idx;
        const float4 qp = cand[ownOff + idx];
        // boundary-corrected tau targeting E[cnt]~26, capped at coverage h
        float r = R_TARGET;
        const float inv2r = 0.5f / r;
        const float fx = (fminf(qp.x + r, 1.f) - fmaxf(qp.x - r, 0.f)) * inv2r;
        const float fy = (fminf(qp.y + r, 1.f) - fmaxf(qp.y - r, 0.f)) * inv2r;
        const float fz = (fminf(qp.z + r, 1.f) - fmaxf(qp.z - r, 0.f)) * inv2r;
        const float f = fmaxf(fx * fy * fz, 0.05f);
        r = R_TARGET * __powf(f, -0.33333334f);
        float tau = fminf(r * r, taumax);
        bool triedMax = (tau >= taumax * 0.999f);

        int cnt = 0;
        bool ok = false;
        for (int att = 0; att < 5 && !ok; ++att) {
            cnt = 0;
            for (int j0 = 0; j0 < nc; j0 += 64) {
                const int j = j0 + lane;
                float d2 = 1e30f;
                unsigned pw = 0;
                if (j < nc) {
                    const float4 pt = cand[j];
                    const float dx = pt.x - qp.x, dy = pt.y - qp.y, dz = pt.z - qp.z;
                    d2 = dx * dx + dy * dy + dz * dz;
                    pw = __float_as_uint(pt.w);
                }
                const bool take = d2 < tau;
                const unsigned long long mm = __ballot(take);
                if (take) {
                    const int pos = cnt + (int)__popcll(mm & laneLt);
                    if (pos < KEY_CAP)
                        keys[wave][pos] =
                            (((unsigned long long)__float_as_uint(d2)) << 32) |
                            (unsigned long long)pw;
                }
                cnt += (int)__popcll(mm);
            }
            if (cnt >= KNN && cnt <= KEY_CAP) ok = true;
            else if (cnt < KNN) {
                if (triedMax) break;                   // needs radius > h -> ladder
                tau = taumax; triedMax = true;
            } else tau *= 0.6f;
        }
        if (!ok) {                                     // boundary points, ~4%
            knn_ladder(sortedPts, cellStart, qp, s, 2, keys[wave], lane, knn_out);
            continue;
        }
        const int m = cnt;
        const unsigned long long k0 = (lane < m) ? keys[wave][lane] : ~0ull;
        const unsigned long long k1 = (lane + 64 < m) ? keys[wave][lane + 64] : ~0ull;
        int r0 = 0, r1 = 0;
        for (int j = 0; j < m; ++j) {
            const unsigned long long kj = keys[wave][j];   // LDS broadcast
            r0 += (kj < k0); r1 += (kj < k1);
        }
        if (lane < m && r0 < KNN)      knn_out[s * KNN + r0] = (int)(unsigned)(k0 & 0xffffffffull);
        if (lane + 64 < m && r1 < KNN) knn_out[s * KNN + r1] = (int)(unsigned)(k1 & 0xffffffffull);
    }
}

// ---------------------------------------------------------------------------
// CRF iteration, SORTED space, 4 lanes/point.
// ---------------------------------------------------------------------------
__global__ __launch_bounds__(256) void crf_iter_kernel(const float* __restrict__ ls,
                                                       const float* __restrict__ W,
                                                       const int* __restrict__ knn,
                                                       const float* __restrict__ qin,
                                                       float* __restrict__ qout,
                                                       const int* __restrict__ orig,
                                                       float* __restrict__ outRef,
                                                       float* __restrict__ outQ) {
    __shared__ float Ws[NCLS * NCLS];
    for (int i = threadIdx.x; i < NCLS * NCLS; i += blockDim.x) Ws[i] = W[i];
    __syncthreads();
    const int t = blockIdx.x * blockDim.x + threadIdx.x;
    const int p = t >> 2;
    const int qtr = t & 3;
    if (p >= N_PTS) return;

    float acc[NCLS];
#pragma unroll
    for (int c = 0; c < NCLS; ++c) acc[c] = 0.f;

    const int4 k4 = ((const int4*)(knn + p * KNN))[qtr];
    const int ids[4] = {k4.x, k4.y, k4.z, k4.w};
#pragma unroll
    for (int u = 0; u < 4; ++u) {
        unsigned id = (unsigned)ids[u];
        if (id >= N_PTS) id = 0;        // safety clamp (unreachable)
        const float4* r4 = (const float4*)(qin + id * NCLS);
#pragma unroll
        for (int v = 0; v < 5; ++v) {
            const float4 a = r4[v];
            acc[4 * v + 0] += a.x; acc[4 * v + 1] += a.y;
            acc[4 * v + 2] += a.z; acc[4 * v + 3] += a.w;
        }
    }
#pragma unroll
    for (int c = 0; c < NCLS; ++c) {
        acc[c] += __shfl_xor(acc[c], 1, 64);
        acc[c] += __shfl_xor(acc[c], 2, 64);
        acc[c] *= (1.f / 16.f);          // msg
    }

    const int c0 = qtr * 5;
    float ref[5];
#pragma unroll
    for (int i = 0; i < 5; ++i) {
        float s = ls[p * NCLS + c0 + i];
#pragma unroll
        for (int k = 0; k < NCLS; ++k) s += acc[k] * Ws[(c0 + i) * NCLS + k];  // x@W^T
        ref[i] = s;
    }

    float mx = ref[0];
#pragma unroll
    for (int i = 1; i < 5; ++i) mx = fmaxf(mx, ref[i]);
    mx = fmaxf(mx, __shfl_xor(mx, 1, 64));
    mx = fmaxf(mx, __shfl_xor(mx, 2, 64));
    float ex[5];
    float ps = 0.f;
#pragma unroll
    for (int i = 0; i < 5; ++i) { ex[i] = __expf(ref[i] - mx); ps += ex[i]; }
    ps += __shfl_xor(ps, 1, 64);
    ps += __shfl_xor(ps, 2, 64);
    const float inv = 1.f / ps;

    if (outRef != nullptr) {
        const int o = orig[p];
#pragma unroll
        for (int i = 0; i < 5; ++i) {
            outRef[o * NCLS + c0 + i] = ref[i];
            outQ[o * NCLS + c0 + i] = ex[i] * inv;
        }
    } else {
#pragma unroll
        for (int i = 0; i < 5; ++i) qout[p * NCLS + c0 + i] = ex[i] * inv;
    }
}

// ---------------------------------------------------------------------------
extern "C" void kernel_launch(void* const* d_in, const int* in_sizes, int n_in,
                              void* d_out, int out_size, void* d_ws, size_t ws_size,
                              hipStream_t stream) {
    const float* logits = (const float*)d_in[0];   // (20000, 20)
    const float* coords = (const float*)d_in[1];   // (20000, 3)
    const float* W      = (const float*)d_in[2];   // (20, 20)
    float* out = (float*)d_out;                    // refined (400000) | q (400000)

    // workspace (~5 MB); q1s aliases out's q-region (safe: final pass reads
    // only q0s/ls/knn/orig and overwrites that region last).
    char* ws = (char*)d_ws;
    size_t off = 0;
    int* knn = (int*)(ws + off);              off += (size_t)N_PTS * KNN * 4;
    off = (off + 255) & ~(size_t)255;
    float* ls = (float*)(ws + off);           off += (size_t)N_PTS * NCLS * 4;
    off = (off + 255) & ~(size_t)255;
    float* q0s = (float*)(ws + off);          off += (size_t)N_PTS * NCLS * 4;
    off = (off + 255) & ~(size_t)255;
    float4* sortedPts = (float4*)(ws + off);  off += (size_t)N_PTS * 16;
    off = (off + 255) & ~(size_t)255;
    int* orig = (int*)(ws + off);             off += (size_t)N_PTS * 4;
    off = (off + 255) & ~(size_t)255;
    int* cellCount = (int*)(ws + off);        off += (size_t)(NCELLS + 1) * 4;
    int* doneCtr = cellCount + NCELLS;        // zeroed with cellCount
    off = (off + 255) & ~(size_t)255;
    int* cellStart = (int*)(ws + off);        off += (size_t)(NCELLS + 1) * 4;
    off = (off + 255) & ~(size_t)255;
    int* cellCursor = (int*)(ws + off);
    float* q1s = out + N_PTS * NCLS;

    const int threads = 256;
    const int pblocks = (N_PTS + threads - 1) / threads;
    const int cblocks = (4 * N_PTS + threads - 1) / threads;

    hipMemsetAsync(cellCount, 0, (NCELLS + 1) * sizeof(int), stream);
    count_scan_kernel<<<pblocks, threads, 0, stream>>>(coords, cellCount, doneCtr,
                                                       cellStart, cellCursor);
    scatter_kernel<<<pblocks, threads, 0, stream>>>(coords, logits, cellCursor,
                                                    sortedPts, orig, ls, q0s);
    knn_kernel<<<NCELLS * 2, threads, 0, stream>>>(sortedPts, cellStart, knn);
    crf_iter_kernel<<<cblocks, threads, 0, stream>>>(ls, W, knn, q0s, q1s, orig,
                                                     nullptr, nullptr);
    crf_iter_kernel<<<cblocks, threads, 0, stream>>>(ls, W, knn, q1s, q0s, orig,
                                                     nullptr, nullptr);
    crf_iter_kernel<<<cblocks, threads, 0, stream>>>(ls, W, knn, q0s, nullptr, orig,
                                                     out, out + N_PTS * NCLS);
}